// Round 9
// baseline (607.674 us; speedup 1.0000x reference)
//
#include <hip/hip_runtime.h>

#define D 128
#define BSHIFT 7          // 128 nodes per bucket
#define CAP 2560          // bucket capacity: lambda=2048, +11 sigma margin
#define LDSPITCH 136      // ushorts/row: 128+8 pad (2-way bank alias = free)

typedef __attribute__((ext_vector_type(8))) short bf16x8;   // 8 bf16 = 4 VGPR
typedef __attribute__((ext_vector_type(4))) float f32x4;    // MFMA acc

__device__ __forceinline__ unsigned short f2bf(float f) {   // fp32 -> bf16 RNE
    union { float f; unsigned int u; } c; c.f = f;
    return (unsigned short)((c.u + 0x7FFFu + ((c.u >> 16) & 1u)) >> 16);
}

// ---------------------------------------------------------------------------
// x (fp32) -> xb (bf16) for the gather.
// ---------------------------------------------------------------------------
__global__ __launch_bounds__(256) void convert_kernel(
    const float* __restrict__ x, unsigned short* __restrict__ xb, int total4)
{
    int gid = blockIdx.x * 256 + threadIdx.x;
    if (gid >= total4) return;
    float4 v = ((const float4*)x)[gid];
    ushort4 o;
    o.x = f2bf(v.x); o.y = f2bf(v.y); o.z = f2bf(v.z); o.w = f2bf(v.w);
    ((ushort4*)xb)[gid] = o;
}

// ---------------------------------------------------------------------------
// W [k][n] fp32 -> Wt [n][k] bf16.
// ---------------------------------------------------------------------------
__global__ __launch_bounds__(256) void convw_kernel(
    const float* __restrict__ W, unsigned short* __restrict__ Wt)
{
    int gid = blockIdx.x * 256 + threadIdx.x;   // 0..16383
    int n = gid >> 7, k = gid & 127;
    Wt[n * 128 + k] = f2bf(W[k * 128 + n]);
}

// ---------------------------------------------------------------------------
// Bucket binning: append packed (dlocal<<17 | src) to bucket (d>>7)'s region.
// Frontier writes are temporally clustered (~nbuck hot lines) -> full-line
// writebacks, unlike per-node-cursor fill whose lines filled over the whole
// kernel (69 MB WRITE for 6.4 MB of data in rounds 4-8).
// Requires src < 2^17 (N=100000 ok).
// ---------------------------------------------------------------------------
__global__ __launch_bounds__(256) void bin_kernel(
    const int* __restrict__ ei, int* __restrict__ cur,
    int* __restrict__ pairs, int E)
{
    int gid = blockIdx.x * 256 + threadIdx.x;
    if (gid >= E) return;
    int d = __builtin_nontemporal_load(&ei[E + gid]);
    int s = __builtin_nontemporal_load(&ei[gid]);
    int b = d >> BSHIFT;
    int pos = atomicAdd(&cur[b], 1);
    if (pos < CAP) pairs[(size_t)b * CAP + pos] = ((d & 127) << 17) | s;
}

// ---------------------------------------------------------------------------
// Exclusive scan of bucket counts -> bbase.  nbuck <= 1024, one block.
// ---------------------------------------------------------------------------
__global__ __launch_bounds__(1024) void bucket_scan(
    const int* __restrict__ cur, int* __restrict__ bbase, int nbuck)
{
    __shared__ int buf[1024];
    int tid = threadIdx.x;
    int v = (tid < nbuck) ? min(cur[tid], CAP) : 0;
    buf[tid] = v;
    __syncthreads();
    for (int off = 1; off < 1024; off <<= 1) {
        int t = (tid >= off) ? buf[tid - off] : 0;
        __syncthreads();
        buf[tid] += t;
        __syncthreads();
    }
    if (tid < nbuck) bbase[tid] = buf[tid] - v;   // exclusive prefix
}

// ---------------------------------------------------------------------------
// Per-bucket local CSR: LDS hist over 128 nodes -> LDS scan -> LDS scatter ->
// coalesced csr write.  Also writes rs (global INCLUSIVE prefix), replacing
// the old hist/scan/fill pipeline entirely.
// ---------------------------------------------------------------------------
__global__ __launch_bounds__(256) void local_fill(
    const int* __restrict__ cur, const int* __restrict__ bbase,
    const int* __restrict__ pairs, int* __restrict__ csr,
    int* __restrict__ rs, int N)
{
    __shared__ int lcnt[128], lofs[128], lincl[128];
    __shared__ int outsrc[CAP];                 // 10 KB
    int b = blockIdx.x;
    int tid = threadIdx.x;
    int cnt = min(cur[b], CAP);
    int base = bbase[b];
    int node0 = b << BSHIFT;
    const int* pp = pairs + (size_t)b * CAP;

    if (tid < 128) lcnt[tid] = 0;
    __syncthreads();
    for (int i = tid; i < cnt; i += 256)
        atomicAdd(&lcnt[pp[i] >> 17], 1);
    __syncthreads();

    // inclusive scan of lcnt over 128 entries (Hillis-Steele in LDS)
    if (tid < 128) lincl[tid] = lcnt[tid];
    __syncthreads();
    for (int off = 1; off < 128; off <<= 1) {
        int t = 0;
        if (tid < 128 && tid >= off) t = lincl[tid - off];
        __syncthreads();
        if (tid < 128) lincl[tid] += t;
        __syncthreads();
    }
    if (tid < 128) lofs[tid] = lincl[tid] - lcnt[tid];  // exclusive
    __syncthreads();

    for (int i = tid; i < cnt; i += 256) {
        int v = pp[i];
        int p = atomicAdd(&lofs[v >> 17], 1);
        outsrc[p] = v & 0x1FFFF;
    }
    __syncthreads();

    for (int i = tid; i < cnt; i += 256)        // coalesced
        csr[base + i] = outsrc[i];
    int nn = N - node0; if (nn > 128) nn = 128;
    if (tid < nn) rs[node0 + tid] = base + lincl[tid];
}

// ---------------------------------------------------------------------------
// Gather + GIN combine: acc = sum_j xb[src_j]; u = (1+eps)*xb[node] + acc,
// bf16 out.  csr via regular loads (4x intra-line reuse).  32 lanes/node.
// ---------------------------------------------------------------------------
__global__ __launch_bounds__(256) void gather_kernel(
    const unsigned short* __restrict__ xb, const float* __restrict__ epsp,
    const int* __restrict__ rs, const int* __restrict__ csr,
    unsigned short* __restrict__ ub, int N)
{
    int sub  = threadIdx.x >> 5;
    int lane = threadIdx.x & 31;
    int node = blockIdx.x * 8 + sub;
    if (node >= N) return;

    int start = (node == 0) ? 0 : rs[node - 1];
    int end   = rs[node];

    float4 acc = make_float4(0.f, 0.f, 0.f, 0.f);
    union { unsigned int u; float f; } c;
    #define BF2F(us) (c.u = ((unsigned int)(us)) << 16, c.f)

    int j = start;
    for (; j + 3 < end; j += 4) {
        int s0 = csr[j], s1 = csr[j + 1], s2 = csr[j + 2], s3 = csr[j + 3];
        ushort4 v0 = ((const ushort4*)(xb + (size_t)s0 * D))[lane];
        ushort4 v1 = ((const ushort4*)(xb + (size_t)s1 * D))[lane];
        ushort4 v2 = ((const ushort4*)(xb + (size_t)s2 * D))[lane];
        ushort4 v3 = ((const ushort4*)(xb + (size_t)s3 * D))[lane];
        acc.x += (BF2F(v0.x) + BF2F(v1.x)) + (BF2F(v2.x) + BF2F(v3.x));
        acc.y += (BF2F(v0.y) + BF2F(v1.y)) + (BF2F(v2.y) + BF2F(v3.y));
        acc.z += (BF2F(v0.z) + BF2F(v1.z)) + (BF2F(v2.z) + BF2F(v3.z));
        acc.w += (BF2F(v0.w) + BF2F(v1.w)) + (BF2F(v2.w) + BF2F(v3.w));
    }
    for (; j < end; ++j) {
        ushort4 v0 = ((const ushort4*)(xb + (size_t)csr[j] * D))[lane];
        acc.x += BF2F(v0.x); acc.y += BF2F(v0.y);
        acc.z += BF2F(v0.z); acc.w += BF2F(v0.w);
    }

    float ep1 = 1.0f + epsp[0];
    ushort4 xr = ((const ushort4*)(xb + (size_t)node * D))[lane];
    acc.x = fmaf(ep1, BF2F(xr.x), acc.x);
    acc.y = fmaf(ep1, BF2F(xr.y), acc.y);
    acc.z = fmaf(ep1, BF2F(xr.z), acc.z);
    acc.w = fmaf(ep1, BF2F(xr.w), acc.w);
    #undef BF2F
    ushort4 o;
    o.x = f2bf(acc.x); o.y = f2bf(acc.y); o.z = f2bf(acc.z); o.w = f2bf(acc.w);
    ((ushort4*)(ub + (size_t)node * D))[lane] = o;
}

// ---------------------------------------------------------------------------
// Fused 2-layer MLP (bf16 MFMA), round-8 verified.
// ---------------------------------------------------------------------------
__global__ __launch_bounds__(256, 2) void mlp_fused(
    const unsigned short* __restrict__ in,
    const unsigned short* __restrict__ W1t, const float* __restrict__ b1,
    const unsigned short* __restrict__ W2t, const float* __restrict__ b2,
    float* __restrict__ out, int N)
{
    __shared__ unsigned short Wl[128 * LDSPITCH];  // 34816 B
    __shared__ unsigned short Al[64 * LDSPITCH];   // 17408 B

    int tid = threadIdx.x;
    int row0 = blockIdx.x * 64;
    int wave = tid >> 6, lane = tid & 63;
    int l16 = lane & 15, lq = lane >> 4;

    for (int i = tid; i < 128 * 16; i += 256) {
        int r = i >> 4, cc = i & 15;
        ((int4*)(Wl + r * LDSPITCH))[cc] = ((const int4*)(W1t + r * 128))[cc];
    }
    for (int i = tid; i < 64 * 16; i += 256) {
        int r = i >> 4, cc = i & 15;
        int4 v = make_int4(0, 0, 0, 0);
        if (row0 + r < N) v = ((const int4*)(in + (size_t)(row0 + r) * 128))[cc];
        ((int4*)(Al + r * LDSPITCH))[cc] = v;
    }
    __syncthreads();

    f32x4 acc[8];
    #pragma unroll
    for (int t = 0; t < 8; ++t) acc[t] = (f32x4){0.f, 0.f, 0.f, 0.f};

    int arow = wave * 16 + l16;
    #pragma unroll
    for (int kk = 0; kk < 4; ++kk) {
        int k0 = kk * 32 + lq * 8;
        bf16x8 a = *(const bf16x8*)(Al + arow * LDSPITCH + k0);
        #pragma unroll
        for (int t = 0; t < 8; ++t) {
            bf16x8 b = *(const bf16x8*)(Wl + (t * 16 + l16) * LDSPITCH + k0);
            acc[t] = __builtin_amdgcn_mfma_f32_16x16x32_bf16(a, b, acc[t], 0, 0, 0);
        }
    }
    __syncthreads();

    for (int i = tid; i < 128 * 16; i += 256) {
        int r = i >> 4, cc = i & 15;
        ((int4*)(Wl + r * LDSPITCH))[cc] = ((const int4*)(W2t + r * 128))[cc];
    }
    #pragma unroll
    for (int t = 0; t < 8; ++t) {
        int col = t * 16 + l16;
        float bv = b1[col];
        #pragma unroll
        for (int r = 0; r < 4; ++r) {
            int row = wave * 16 + lq * 4 + r;
            float v = fmaxf(acc[t][r] + bv, 0.0f);
            Al[row * LDSPITCH + col] = f2bf(v);
        }
    }
    __syncthreads();

    #pragma unroll
    for (int t = 0; t < 8; ++t) acc[t] = (f32x4){0.f, 0.f, 0.f, 0.f};
    #pragma unroll
    for (int kk = 0; kk < 4; ++kk) {
        int k0 = kk * 32 + lq * 8;
        bf16x8 a = *(const bf16x8*)(Al + arow * LDSPITCH + k0);
        #pragma unroll
        for (int t = 0; t < 8; ++t) {
            bf16x8 b = *(const bf16x8*)(Wl + (t * 16 + l16) * LDSPITCH + k0);
            acc[t] = __builtin_amdgcn_mfma_f32_16x16x32_bf16(a, b, acc[t], 0, 0, 0);
        }
    }

    #pragma unroll
    for (int t = 0; t < 8; ++t) {
        int col = t * 16 + l16;
        float bv = b2[col];
        #pragma unroll
        for (int r = 0; r < 4; ++r) {
            int row = row0 + wave * 16 + lq * 4 + r;
            if (row >= N) continue;
            out[(size_t)row * 128 + col] = acc[t][r] + bv;
        }
    }
}

extern "C" void kernel_launch(void* const* d_in, const int* in_sizes, int n_in,
                              void* d_out, int out_size, void* d_ws, size_t ws_size,
                              hipStream_t stream) {
    const float* x   = (const float*)d_in[0];
    const int*   ei  = (const int*)d_in[1];    // edge_index [2][E]
    const float* eps = (const float*)d_in[2];
    const float* W1  = (const float*)d_in[3];
    const float* b1  = (const float*)d_in[4];
    const float* W2  = (const float*)d_in[5];
    const float* b2  = (const float*)d_in[6];
    float* out = (float*)d_out;

    int E = in_sizes[1] / 2;                   // 1,600,000
    int N = in_sizes[0] / D;                   // 100,000
    int nbuck = (N + 127) >> BSHIFT;           // 782

    // workspace layout (bytes):
    //   [0, 4096)                cur   int[nbuck]
    //   [4096, 8192)             bbase int[nbuck]
    //   [8192, 408192)           rs    int[N]
    //   [409600, 8417280)        pairs int[nbuck*CAP]   (8 MB)
    //   [8417280, 14817280)      csr   int[E]
    //   [14817280, 40417280)     xb    bf16[N*D]
    //   [40417280, 66017280)     ub    bf16[N*D]
    //   [66017280, +32768)       W1t   bf16[128*128]
    //   [66050048, +32768)       W2t   bf16[128*128]
    char* ws = (char*)d_ws;
    int* cur   = (int*)(ws);
    int* bbase = (int*)(ws + 4096);
    int* rs    = (int*)(ws + 8192);
    int* pairs = (int*)(ws + 409600);
    int* csr   = (int*)(ws + 8417280);
    unsigned short* xb  = (unsigned short*)(ws + 14817280);
    unsigned short* ub  = (unsigned short*)(ws + 40417280);
    unsigned short* W1t = (unsigned short*)(ws + 66017280);
    unsigned short* W2t = (unsigned short*)(ws + 66050048);

    hipMemsetAsync(cur, 0, nbuck * sizeof(int), stream);

    int total4 = N * D / 4;
    convert_kernel<<<(total4 + 255) / 256, 256, 0, stream>>>(x, xb, total4);
    convw_kernel<<<64, 256, 0, stream>>>(W1, W1t);
    convw_kernel<<<64, 256, 0, stream>>>(W2, W2t);

    bin_kernel<<<(E + 255) / 256, 256, 0, stream>>>(ei, cur, pairs, E);
    bucket_scan<<<1, 1024, 0, stream>>>(cur, bbase, nbuck);
    local_fill<<<nbuck, 256, 0, stream>>>(cur, bbase, pairs, csr, rs, N);

    gather_kernel<<<(N + 7) / 8, 256, 0, stream>>>(xb, eps, rs, csr, ub, N);

    int gemm_blocks = (N + 63) / 64;           // 1563
    mlp_fused<<<gemm_blocks, 256, 0, stream>>>(ub, W1t, b1, W2t, b2, out, N);
}

// Round 10
// 312.193 us; speedup vs baseline: 1.9465x; 1.9465x over previous
//
#include <hip/hip_runtime.h>

#define D 128
#define BSHIFT 7          // 128 nodes per bucket
#define NSUB 8            // sub-buckets per bucket, keyed by blockIdx&7 (XCD)
#define SUBCAP 384        // per-sub-bucket capacity: lambda=256, +8 sigma
#define CAP 2560          // whole-bucket LDS staging: lambda=2048, +11 sigma
#define LDSPITCH 136      // ushorts/row: 128+8 pad (2-way bank alias = free)

typedef __attribute__((ext_vector_type(8))) short bf16x8;   // 8 bf16 = 4 VGPR
typedef __attribute__((ext_vector_type(4))) float f32x4;    // MFMA acc

__device__ __forceinline__ unsigned short f2bf(float f) {   // fp32 -> bf16 RNE
    union { float f; unsigned int u; } c; c.f = f;
    return (unsigned short)((c.u + 0x7FFFu + ((c.u >> 16) & 1u)) >> 16);
}

// ---------------------------------------------------------------------------
// x (fp32) -> xb (bf16) for the gather.
// ---------------------------------------------------------------------------
__global__ __launch_bounds__(256) void convert_kernel(
    const float* __restrict__ x, unsigned short* __restrict__ xb, int total4)
{
    int gid = blockIdx.x * 256 + threadIdx.x;
    if (gid >= total4) return;
    float4 v = ((const float4*)x)[gid];
    ushort4 o;
    o.x = f2bf(v.x); o.y = f2bf(v.y); o.z = f2bf(v.z); o.w = f2bf(v.w);
    ((ushort4*)xb)[gid] = o;
}

// ---------------------------------------------------------------------------
// W [k][n] fp32 -> Wt [n][k] bf16.
// ---------------------------------------------------------------------------
__global__ __launch_bounds__(256) void convw_kernel(
    const float* __restrict__ W, unsigned short* __restrict__ Wt)
{
    int gid = blockIdx.x * 256 + threadIdx.x;   // 0..16383
    int n = gid >> 7, k = gid & 127;
    Wt[n * 128 + k] = f2bf(W[k * 128 + n]);
}

// ---------------------------------------------------------------------------
// Bucket binning, per-slice sub-buckets.  Round-9 lessons baked in:
//  (a) cur[b*8+slice] is touched only by blocks with blockIdx&7==slice
//      (~one XCD) -> L2-local atomics, ~256 adds/counter (was 2000
//      cross-XCD adds/counter = 378 us of coherence serialization);
//  (b) sub-region (b,slice) has a single-XCD write frontier -> full-line
//      writebacks (was 8 partial copies across 8 non-coherent L2s = 69 MB).
// Packs (dlocal<<17 | src); needs src < 2^17 (N=100000 ok).
// ---------------------------------------------------------------------------
__global__ __launch_bounds__(256) void bin_kernel(
    const int* __restrict__ ei, int* __restrict__ cur,
    int* __restrict__ pairs, int E)
{
    int slice = blockIdx.x & (NSUB - 1);
    int gid = blockIdx.x * 256 + threadIdx.x;
    if (gid >= E) return;
    int d = __builtin_nontemporal_load(&ei[E + gid]);
    int s = __builtin_nontemporal_load(&ei[gid]);
    int b = d >> BSHIFT;
    int sb = b * NSUB + slice;
    int pos = atomicAdd(&cur[sb], 1);
    if (pos < SUBCAP) pairs[(size_t)sb * SUBCAP + pos] = ((d & 127) << 17) | s;
}

// ---------------------------------------------------------------------------
// Exclusive scan over per-bucket totals (sum of 8 sub-counts).  One block.
// ---------------------------------------------------------------------------
__global__ __launch_bounds__(1024) void bucket_scan(
    const int* __restrict__ cur, int* __restrict__ bbase, int nbuck)
{
    __shared__ int buf[1024];
    int tid = threadIdx.x;
    int v = 0;
    if (tid < nbuck) {
        #pragma unroll
        for (int s = 0; s < NSUB; ++s) v += min(cur[tid * NSUB + s], SUBCAP);
    }
    buf[tid] = v;
    __syncthreads();
    for (int off = 1; off < 1024; off <<= 1) {
        int t = (tid >= off) ? buf[tid - off] : 0;
        __syncthreads();
        buf[tid] += t;
        __syncthreads();
    }
    if (tid < nbuck) bbase[tid] = buf[tid] - v;   // exclusive prefix
}

// ---------------------------------------------------------------------------
// Per-bucket local CSR: concat 8 sub-lists into LDS -> LDS hist over the
// bucket's 128 nodes -> LDS scan -> LDS scatter -> coalesced csr write.
// Writes rs as global INCLUSIVE prefix.
// ---------------------------------------------------------------------------
__global__ __launch_bounds__(256) void local_fill(
    const int* __restrict__ cur, const int* __restrict__ bbase,
    const int* __restrict__ pairs, int* __restrict__ csr,
    int* __restrict__ rs, int N)
{
    __shared__ int ldata[CAP];                  // 10 KB packed pairs
    __shared__ int outsrc[CAP];                 // 10 KB scattered srcs
    __shared__ int lcnt[128], lofs[128], lincl[128];

    int b = blockIdx.x;
    int tid = threadIdx.x;
    int base = bbase[b];
    int node0 = b << BSHIFT;

    // concat sub-lists
    int off = 0;
    #pragma unroll
    for (int s = 0; s < NSUB; ++s) {
        int c = min(cur[b * NSUB + s], SUBCAP);
        const int* pp = pairs + (size_t)(b * NSUB + s) * SUBCAP;
        for (int i = tid; i < c && off + i < CAP; i += 256)
            ldata[off + i] = pp[i];
        off += c;
    }
    int cnt = min(off, CAP);
    __syncthreads();

    if (tid < 128) lcnt[tid] = 0;
    __syncthreads();
    for (int i = tid; i < cnt; i += 256)
        atomicAdd(&lcnt[ldata[i] >> 17], 1);
    __syncthreads();

    // inclusive scan of lcnt over 128 entries
    if (tid < 128) lincl[tid] = lcnt[tid];
    __syncthreads();
    for (int off2 = 1; off2 < 128; off2 <<= 1) {
        int t = 0;
        if (tid < 128 && tid >= off2) t = lincl[tid - off2];
        __syncthreads();
        if (tid < 128) lincl[tid] += t;
        __syncthreads();
    }
    if (tid < 128) lofs[tid] = lincl[tid] - lcnt[tid];  // exclusive
    __syncthreads();

    for (int i = tid; i < cnt; i += 256) {
        int v = ldata[i];
        int p = atomicAdd(&lofs[v >> 17], 1);
        outsrc[p] = v & 0x1FFFF;
    }
    __syncthreads();

    for (int i = tid; i < cnt; i += 256)        // coalesced
        csr[base + i] = outsrc[i];
    int nn = N - node0; if (nn > 128) nn = 128;
    if (tid < nn) rs[node0 + tid] = base + lincl[tid];
}

// ---------------------------------------------------------------------------
// Gather + GIN combine: acc = sum_j xb[src_j]; u = (1+eps)*xb[node] + acc,
// bf16 out.  csr via regular loads (4x intra-line reuse).  32 lanes/node.
// ---------------------------------------------------------------------------
__global__ __launch_bounds__(256) void gather_kernel(
    const unsigned short* __restrict__ xb, const float* __restrict__ epsp,
    const int* __restrict__ rs, const int* __restrict__ csr,
    unsigned short* __restrict__ ub, int N)
{
    int sub  = threadIdx.x >> 5;
    int lane = threadIdx.x & 31;
    int node = blockIdx.x * 8 + sub;
    if (node >= N) return;

    int start = (node == 0) ? 0 : rs[node - 1];
    int end   = rs[node];

    float4 acc = make_float4(0.f, 0.f, 0.f, 0.f);
    union { unsigned int u; float f; } c;
    #define BF2F(us) (c.u = ((unsigned int)(us)) << 16, c.f)

    int j = start;
    for (; j + 3 < end; j += 4) {
        int s0 = csr[j], s1 = csr[j + 1], s2 = csr[j + 2], s3 = csr[j + 3];
        ushort4 v0 = ((const ushort4*)(xb + (size_t)s0 * D))[lane];
        ushort4 v1 = ((const ushort4*)(xb + (size_t)s1 * D))[lane];
        ushort4 v2 = ((const ushort4*)(xb + (size_t)s2 * D))[lane];
        ushort4 v3 = ((const ushort4*)(xb + (size_t)s3 * D))[lane];
        acc.x += (BF2F(v0.x) + BF2F(v1.x)) + (BF2F(v2.x) + BF2F(v3.x));
        acc.y += (BF2F(v0.y) + BF2F(v1.y)) + (BF2F(v2.y) + BF2F(v3.y));
        acc.z += (BF2F(v0.z) + BF2F(v1.z)) + (BF2F(v2.z) + BF2F(v3.z));
        acc.w += (BF2F(v0.w) + BF2F(v1.w)) + (BF2F(v2.w) + BF2F(v3.w));
    }
    for (; j < end; ++j) {
        ushort4 v0 = ((const ushort4*)(xb + (size_t)csr[j] * D))[lane];
        acc.x += BF2F(v0.x); acc.y += BF2F(v0.y);
        acc.z += BF2F(v0.z); acc.w += BF2F(v0.w);
    }

    float ep1 = 1.0f + epsp[0];
    ushort4 xr = ((const ushort4*)(xb + (size_t)node * D))[lane];
    acc.x = fmaf(ep1, BF2F(xr.x), acc.x);
    acc.y = fmaf(ep1, BF2F(xr.y), acc.y);
    acc.z = fmaf(ep1, BF2F(xr.z), acc.z);
    acc.w = fmaf(ep1, BF2F(xr.w), acc.w);
    #undef BF2F
    ushort4 o;
    o.x = f2bf(acc.x); o.y = f2bf(acc.y); o.z = f2bf(acc.z); o.w = f2bf(acc.w);
    ((ushort4*)(ub + (size_t)node * D))[lane] = o;
}

// ---------------------------------------------------------------------------
// Fused 2-layer MLP (bf16 MFMA), round-8 verified.
// ---------------------------------------------------------------------------
__global__ __launch_bounds__(256, 2) void mlp_fused(
    const unsigned short* __restrict__ in,
    const unsigned short* __restrict__ W1t, const float* __restrict__ b1,
    const unsigned short* __restrict__ W2t, const float* __restrict__ b2,
    float* __restrict__ out, int N)
{
    __shared__ unsigned short Wl[128 * LDSPITCH];  // 34816 B
    __shared__ unsigned short Al[64 * LDSPITCH];   // 17408 B

    int tid = threadIdx.x;
    int row0 = blockIdx.x * 64;
    int wave = tid >> 6, lane = tid & 63;
    int l16 = lane & 15, lq = lane >> 4;

    for (int i = tid; i < 128 * 16; i += 256) {
        int r = i >> 4, cc = i & 15;
        ((int4*)(Wl + r * LDSPITCH))[cc] = ((const int4*)(W1t + r * 128))[cc];
    }
    for (int i = tid; i < 64 * 16; i += 256) {
        int r = i >> 4, cc = i & 15;
        int4 v = make_int4(0, 0, 0, 0);
        if (row0 + r < N) v = ((const int4*)(in + (size_t)(row0 + r) * 128))[cc];
        ((int4*)(Al + r * LDSPITCH))[cc] = v;
    }
    __syncthreads();

    f32x4 acc[8];
    #pragma unroll
    for (int t = 0; t < 8; ++t) acc[t] = (f32x4){0.f, 0.f, 0.f, 0.f};

    int arow = wave * 16 + l16;
    #pragma unroll
    for (int kk = 0; kk < 4; ++kk) {
        int k0 = kk * 32 + lq * 8;
        bf16x8 a = *(const bf16x8*)(Al + arow * LDSPITCH + k0);
        #pragma unroll
        for (int t = 0; t < 8; ++t) {
            bf16x8 b = *(const bf16x8*)(Wl + (t * 16 + l16) * LDSPITCH + k0);
            acc[t] = __builtin_amdgcn_mfma_f32_16x16x32_bf16(a, b, acc[t], 0, 0, 0);
        }
    }
    __syncthreads();

    for (int i = tid; i < 128 * 16; i += 256) {
        int r = i >> 4, cc = i & 15;
        ((int4*)(Wl + r * LDSPITCH))[cc] = ((const int4*)(W2t + r * 128))[cc];
    }
    #pragma unroll
    for (int t = 0; t < 8; ++t) {
        int col = t * 16 + l16;
        float bv = b1[col];
        #pragma unroll
        for (int r = 0; r < 4; ++r) {
            int row = wave * 16 + lq * 4 + r;
            float v = fmaxf(acc[t][r] + bv, 0.0f);
            Al[row * LDSPITCH + col] = f2bf(v);
        }
    }
    __syncthreads();

    #pragma unroll
    for (int t = 0; t < 8; ++t) acc[t] = (f32x4){0.f, 0.f, 0.f, 0.f};
    #pragma unroll
    for (int kk = 0; kk < 4; ++kk) {
        int k0 = kk * 32 + lq * 8;
        bf16x8 a = *(const bf16x8*)(Al + arow * LDSPITCH + k0);
        #pragma unroll
        for (int t = 0; t < 8; ++t) {
            bf16x8 b = *(const bf16x8*)(Wl + (t * 16 + l16) * LDSPITCH + k0);
            acc[t] = __builtin_amdgcn_mfma_f32_16x16x32_bf16(a, b, acc[t], 0, 0, 0);
        }
    }

    #pragma unroll
    for (int t = 0; t < 8; ++t) {
        int col = t * 16 + l16;
        float bv = b2[col];
        #pragma unroll
        for (int r = 0; r < 4; ++r) {
            int row = row0 + wave * 16 + lq * 4 + r;
            if (row >= N) continue;
            out[(size_t)row * 128 + col] = acc[t][r] + bv;
        }
    }
}

extern "C" void kernel_launch(void* const* d_in, const int* in_sizes, int n_in,
                              void* d_out, int out_size, void* d_ws, size_t ws_size,
                              hipStream_t stream) {
    const float* x   = (const float*)d_in[0];
    const int*   ei  = (const int*)d_in[1];    // edge_index [2][E]
    const float* eps = (const float*)d_in[2];
    const float* W1  = (const float*)d_in[3];
    const float* b1  = (const float*)d_in[4];
    const float* W2  = (const float*)d_in[5];
    const float* b2  = (const float*)d_in[6];
    float* out = (float*)d_out;

    int E = in_sizes[1] / 2;                   // 1,600,000
    int N = in_sizes[0] / D;                   // 100,000
    int nbuck = (N + 127) >> BSHIFT;           // 782

    // workspace layout (bytes):
    //   [0, 28672)               cur   int[nbuck*8]   (25,024 used)
    //   [28672, 32768)           bbase int[nbuck]
    //   [32768, 432768)          rs    int[N]
    //   [434176, 10043392)       pairs int[nbuck*8*SUBCAP]  (9.6 MB)
    //   [10044416, 16444416)     csr   int[E]
    //   [16445440, 42045440)     xb    bf16[N*D]
    //   [42046464, 67646464)     ub    bf16[N*D]
    //   [67647488, +32768)       W1t   bf16[128*128]
    //   [67680256, +32768)       W2t   bf16[128*128]
    char* ws = (char*)d_ws;
    int* cur   = (int*)(ws);
    int* bbase = (int*)(ws + 28672);
    int* rs    = (int*)(ws + 32768);
    int* pairs = (int*)(ws + 434176);
    int* csr   = (int*)(ws + 10044416);
    unsigned short* xb  = (unsigned short*)(ws + 16445440);
    unsigned short* ub  = (unsigned short*)(ws + 42046464);
    unsigned short* W1t = (unsigned short*)(ws + 67647488);
    unsigned short* W2t = (unsigned short*)(ws + 67680256);

    hipMemsetAsync(cur, 0, (size_t)nbuck * NSUB * sizeof(int), stream);

    int total4 = N * D / 4;
    convert_kernel<<<(total4 + 255) / 256, 256, 0, stream>>>(x, xb, total4);
    convw_kernel<<<64, 256, 0, stream>>>(W1, W1t);
    convw_kernel<<<64, 256, 0, stream>>>(W2, W2t);

    bin_kernel<<<(E + 255) / 256, 256, 0, stream>>>(ei, cur, pairs, E);
    bucket_scan<<<1, 1024, 0, stream>>>(cur, bbase, nbuck);
    local_fill<<<nbuck, 256, 0, stream>>>(cur, bbase, pairs, csr, rs, N);

    gather_kernel<<<(N + 7) / 8, 256, 0, stream>>>(xb, eps, rs, csr, ub, N);

    int gemm_blocks = (N + 63) / 64;           // 1563
    mlp_fused<<<gemm_blocks, 256, 0, stream>>>(ub, W1t, b1, W2t, b2, out, N);
}